// Round 4
// baseline (1247.298 us; speedup 1.0000x reference)
//
#include <hip/hip_runtime.h>

// Problem constants (from reference setup_inputs) — all tensors are fp32.
#define BATCH 16
#define NVEC 1024
#define NDIM 64
#define NHID 32
#define NW   10
#define NCLS 10
#define NOFF 11      // diag + 10 power-of-2 offsets (chord mask: 11 nnz/row)
#define WPAD 12      // padded weights-per-row so k_chain reads 3x float4

// ---------------------------------------------------------------------------
// Kernel 0: transpose fW2 [i][j][m] -> W2T [i][m][j] so the k_weights gather
// reads 8 consecutive j's as 2 float4 per (row, offset). LDS-tiled, 1.3 MB.
// grid (16 m-tiles, NW), block 256 (4 waves).
// ---------------------------------------------------------------------------
__global__ __launch_bounds__(256) void k_transpose(
    const float* __restrict__ fW2, float* __restrict__ W2T)
{
    __shared__ float tile[NHID][65];   // +1 pad: conflict-free transposed reads
    const int i = blockIdx.y;
    const int m0 = blockIdx.x * 64;
    const int t = threadIdx.x;
    const int tL = t & 63, wv = t >> 6;

    const float* src = fW2 + (size_t)i * NHID * NVEC;
    #pragma unroll
    for (int jj = 0; jj < 8; ++jj) {
        int j = wv * 8 + jj;
        tile[j][tL] = src[(size_t)j * NVEC + m0 + tL];   // 256B coalesced
    }
    __syncthreads();

    float* dst = W2T + (size_t)i * NVEC * NHID;
    const int j = t & 31, mrow = t >> 5;
    #pragma unroll
    for (int g = 0; g < 8; ++g) {
        int m = g * 8 + mrow;
        dst[(size_t)(m0 + m) * NHID + j] = tile[j][m];   // coalesced
    }
}

// ---------------------------------------------------------------------------
// Kernel 1: all sparse W entries for all 10 layers (h depends only on data).
// Thread = (4 rows) x (8 hidden units, q = lane&3 quarter). Each sW1 LDS read
// feeds 4 rows of FMA (round-3 version re-read LDS per FMA group -> 25us of
// ds_read issue). Partial w[o] over 8 j's combined across q via 2x shfl_xor.
// Wsp[i][b][n][o] (WPAD=12) so k_chain reads 3 float4 per row-layer.
// grid (4, BATCH, NW), block 256.
// ---------------------------------------------------------------------------
__global__ __launch_bounds__(256, 4) void k_weights(
    const float* __restrict__ data,   // [B][NVEC][NDIM]
    const float* __restrict__ fW1,    // [NW][NDIM][NHID]
    const float* __restrict__ fb1,    // [NW][NHID]
    const float* __restrict__ W2T,    // [NW][NVEC][NHID]  (transposed fW2)
    const float* __restrict__ fb2,    // [NW][NVEC]
    float* __restrict__ Wsp)          // [NW][B][NVEC][WPAD]
{
    const int i = blockIdx.z;
    const int b = blockIdx.y;
    const int t = threadIdx.x;
    const int q  = t & 3;             // j-quarter: j0 = 8q
    const int nl = t >> 2;            // 0..63
    const int nbase = blockIdx.x * 256;

    __shared__ float sW1[NDIM * NHID];
    __shared__ float sb1[NHID];
    {
        const float4* w1v = (const float4*)(fW1 + (size_t)i * NDIM * NHID);
        float4* s4 = (float4*)sW1;
        for (int k = t; k < NDIM * NHID / 4; k += 256) s4[k] = w1v[k];
        if (t < NHID) sb1[t] = fb1[i * NHID + t];
    }
    __syncthreads();

    const int j0 = q * 8;
    float h[4][8];
    #pragma unroll
    for (int r = 0; r < 4; ++r)
        #pragma unroll
        for (int jj = 0; jj < 8; ++jj) h[r][jj] = sb1[j0 + jj];

    const float* drow = data + ((size_t)(b * NVEC) + nbase + nl) * NDIM;
    #pragma unroll
    for (int g = 0; g < 16; ++g) {        // groups of 4 d-dims
        float4 wv[4][2];
        #pragma unroll
        for (int d2 = 0; d2 < 4; ++d2) {
            const float4* p = (const float4*)(&sW1[(g * 4 + d2) * NHID + j0]);
            wv[d2][0] = p[0]; wv[d2][1] = p[1];
        }
        #pragma unroll
        for (int r = 0; r < 4; ++r) {
            float4 u = ((const float4*)(drow + (size_t)r * 64 * NDIM))[g];
            float xs[4] = {u.x, u.y, u.z, u.w};
            #pragma unroll
            for (int d2 = 0; d2 < 4; ++d2) {
                float x = xs[d2];
                const float* wf = (const float*)&wv[d2][0];
                #pragma unroll
                for (int jj = 0; jj < 8; ++jj) h[r][jj] += x * wf[jj];
            }
        }
    }

    // exact gelu on the 32 h's
    #pragma unroll
    for (int r = 0; r < 4; ++r)
        #pragma unroll
        for (int jj = 0; jj < 8; ++jj) {
            float x = h[r][jj];
            h[r][jj] = 0.5f * x * (1.0f + erff(x * 0.70710678118654752f));
        }

    const float* w2t = W2T + (size_t)i * NVEC * NHID;
    const float* b2  = fb2 + (size_t)i * NVEC;
    #pragma unroll
    for (int r = 0; r < 4; ++r) {
        const int n = nbase + nl + 64 * r;
        float w[NOFF];
        int m[NOFF];
        #pragma unroll
        for (int o = 0; o < NOFF; ++o) {
            int off = (o == 0) ? 0 : (1 << (o - 1));
            m[o] = (n + off) & (NVEC - 1);
            w[o] = 0.0f;
        }
        #pragma unroll
        for (int o = 0; o < NOFF; ++o) {
            const float4* gp = (const float4*)(w2t + (size_t)m[o] * NHID + j0);
            float4 g0 = gp[0], g1 = gp[1];
            w[o] += h[r][0] * g0.x + h[r][1] * g0.y + h[r][2] * g0.z + h[r][3] * g0.w
                  + h[r][4] * g1.x + h[r][5] * g1.y + h[r][6] * g1.z + h[r][7] * g1.w;
        }
        // combine the 4 j-quarters (lanes nl*4 + q: xor 1, xor 2)
        #pragma unroll
        for (int o = 0; o < NOFF; ++o) {
            w[o] += __shfl_xor(w[o], 1, 64);
            w[o] += __shfl_xor(w[o], 2, 64);
        }
        float* wout = Wsp + ((size_t)(i * BATCH + b) * NVEC + n) * WPAD;
        #pragma unroll
        for (int o = q; o < NOFF; o += 4) wout[o] = w[o] + b2[m[o]];
    }
}

// ---------------------------------------------------------------------------
// Kernel 2: FUSED 10-layer chain + final-projection partials.
// Block = (b, 4-dim chunk): V[1024][4] slice closed under the chord gather,
// kept in LDS float4 (all gathers aligned ds_read_b128, conflict-free).
// 1024 threads = 16 waves/CU (round 3 had 4 -> latency-bound). Next layer's
// 11 weights (3 float4, row-padded) prefetched into registers so the loads
// are in flight across the barrier. 1 barrier/layer.
// grid (16 chunks, BATCH), block 1024.
// ---------------------------------------------------------------------------
__global__ __launch_bounds__(1024, 4) void k_chain(
    const float* __restrict__ data,   // [B][NVEC][NDIM]
    const float* __restrict__ Wsp,    // [NW][B][NVEC][WPAD]
    const float* __restrict__ Wf,     // [NVEC*NDIM][NCLS]
    float* __restrict__ part)         // [B][16][NCLS]
{
    const int chunk = blockIdx.x;
    const int b     = blockIdx.y;
    const int d0    = chunk * 4;
    const int n     = threadIdx.x;

    __shared__ float4 bufA[NVEC];
    __shared__ float4 bufB[NVEC];

    bufA[n] = *(const float4*)(data + ((size_t)(b * NVEC) + n) * NDIM + d0);

    // prefetch layer NW-1 weights
    const float4* wp = (const float4*)(Wsp + ((size_t)((NW - 1) * BATCH + b) * NVEC + n) * WPAD);
    float4 wa = wp[0], wb4 = wp[1], wc = wp[2];
    __syncthreads();

    float4* cur = bufA;
    float4* nxt = bufB;

    for (int l = 0; l < NW; ++l) {
        float4 na, nb, nc;
        if (l < NW - 1) {   // prefetch next layer (stays in flight across barrier)
            const float4* wpn = (const float4*)(
                Wsp + ((size_t)((NW - 2 - l) * BATCH + b) * NVEC + n) * WPAD);
            na = wpn[0]; nb = wpn[1]; nc = wpn[2];
        }
        const float wgt[12] = {wa.x, wa.y, wa.z, wa.w,
                               wb4.x, wb4.y, wb4.z, wb4.w,
                               wc.x, wc.y, wc.z, wc.w};
        float4 v0 = cur[n];
        float4 acc;
        acc.x = v0.x + wgt[0] * v0.x;
        acc.y = v0.y + wgt[0] * v0.y;
        acc.z = v0.z + wgt[0] * v0.z;
        acc.w = v0.w + wgt[0] * v0.w;
        #pragma unroll
        for (int o = 1; o < NOFF; ++o) {
            int off = 1 << (o - 1);
            float4 vv = cur[(n + off) & (NVEC - 1)];
            acc.x += wgt[o] * vv.x; acc.y += wgt[o] * vv.y;
            acc.z += wgt[o] * vv.z; acc.w += wgt[o] * vv.w;
        }
        nxt[n] = acc;
        __syncthreads();
        float4* tmp = cur; cur = nxt; nxt = tmp;
        if (l < NW - 1) { wa = na; wb4 = nb; wc = nc; }
    }
    // after 10 swaps cur == bufA holds final V slice

    // fused final projection partial over this (b, d-chunk)
    float p[NCLS];
    #pragma unroll
    for (int c = 0; c < NCLS; ++c) p[c] = 0.0f;
    {
        float4 vv = cur[n];
        float vs[4] = {vv.x, vv.y, vv.z, vv.w};
        const float4* wfv = (const float4*)(Wf + ((size_t)(n * NDIM + d0)) * NCLS);
        float wf[40];
        #pragma unroll
        for (int k = 0; k < 10; ++k) {
            float4 u = wfv[k];
            wf[k * 4 + 0] = u.x; wf[k * 4 + 1] = u.y;
            wf[k * 4 + 2] = u.z; wf[k * 4 + 3] = u.w;
        }
        #pragma unroll
        for (int d = 0; d < 4; ++d)
            #pragma unroll
            for (int cls = 0; cls < NCLS; ++cls)
                p[cls] += vs[d] * wf[d * NCLS + cls];
    }

    // reduce 1024 threads -> 10 values: wave shfl then cross-wave via LDS
    const int lane = n & 63, wv = n >> 6;   // 16 waves
    float* sred = (float*)nxt;              // dead buffer
    #pragma unroll
    for (int cls = 0; cls < NCLS; ++cls) {
        float v = p[cls];
        #pragma unroll
        for (int s = 32; s > 0; s >>= 1) v += __shfl_down(v, s, 64);
        if (lane == 0) sred[wv * NCLS + cls] = v;
    }
    __syncthreads();
    if (n < NCLS) {
        float s = 0.0f;
        #pragma unroll
        for (int w = 0; w < 16; ++w) s += sred[w * NCLS + n];
        part[(size_t)(b * 16 + chunk) * NCLS + n] = s;
    }
}

// ---------------------------------------------------------------------------
__global__ __launch_bounds__(256) void k_finish(
    const float* __restrict__ part, const float* __restrict__ bias,
    float* __restrict__ out)
{
    int t = threadIdx.x;
    if (t < BATCH * NCLS) {
        int b = t / NCLS, cls = t % NCLS;
        float s = bias[cls];
        #pragma unroll
        for (int ch = 0; ch < 16; ++ch) s += part[(size_t)(b * 16 + ch) * NCLS + cls];
        out[t] = s;
    }
}

// ---------------------------------------------------------------------------
extern "C" void kernel_launch(void* const* d_in, const int* in_sizes, int n_in,
                              void* d_out, int out_size, void* d_ws, size_t ws_size,
                              hipStream_t stream) {
    const float* data = (const float*)d_in[0];
    const float* fW1  = (const float*)d_in[1];
    const float* fb1  = (const float*)d_in[2];
    const float* fW2  = (const float*)d_in[3];
    const float* fb2  = (const float*)d_in[4];
    const float* fWf  = (const float*)d_in[5];
    const float* fbf  = (const float*)d_in[6];
    float* out = (float*)d_out;

    float* ws   = (float*)d_ws;
    float* Wsp  = ws;                                         // NW*B*NVEC*WPAD = 1,966,080 f
    float* W2T  = Wsp + (size_t)NW * BATCH * NVEC * WPAD;     // NW*NVEC*NHID  =   327,680 f
    float* part = W2T + (size_t)NW * NVEC * NHID;             // 2,560 f

    k_transpose<<<dim3(NVEC / 64, NW), 256, 0, stream>>>(fW2, W2T);
    k_weights<<<dim3(NVEC / 256, BATCH, NW), 256, 0, stream>>>(
        data, fW1, fb1, W2T, fb2, Wsp);
    k_chain<<<dim3(NDIM / 4, BATCH), 1024, 0, stream>>>(data, Wsp, fWf, part);
    k_finish<<<dim3(1), 256, 0, stream>>>(part, fbf, out);
}

// Round 5
// 130.030 us; speedup vs baseline: 9.5924x; 9.5924x over previous
//
#include <hip/hip_runtime.h>

// Problem constants (from reference setup_inputs) — all tensors are fp32.
#define BATCH 16
#define NVEC 1024
#define NDIM 64
#define NHID 32
#define NW   10
#define NCLS 10
#define NOFF 11      // diag + 10 power-of-2 offsets (chord mask: 11 nnz/row)
#define WPAD 12      // padded weights-per-row so k_chain reads 3x float4

// ---------------------------------------------------------------------------
// Kernel 0: transpose fW2 [i][j][m] -> W2T [i][m][j] so the k_weights gather
// reads 8 consecutive j's as 2 float4 per (row, offset). LDS-tiled, 1.3 MB.
// ---------------------------------------------------------------------------
__global__ __launch_bounds__(256) void k_transpose(
    const float* __restrict__ fW2, float* __restrict__ W2T)
{
    __shared__ float tile[NHID][65];   // +1 pad: conflict-free transposed reads
    const int i = blockIdx.y;
    const int m0 = blockIdx.x * 64;
    const int t = threadIdx.x;
    const int tL = t & 63, wv = t >> 6;

    const float* src = fW2 + (size_t)i * NHID * NVEC;
    #pragma unroll
    for (int jj = 0; jj < 8; ++jj) {
        int j = wv * 8 + jj;
        tile[j][tL] = src[(size_t)j * NVEC + m0 + tL];   // 256B coalesced
    }
    __syncthreads();

    float* dst = W2T + (size_t)i * NVEC * NHID;
    const int j = t & 31, mrow = t >> 5;
    #pragma unroll
    for (int g = 0; g < 8; ++g) {
        int m = g * 8 + mrow;
        dst[(size_t)(m0 + m) * NHID + j] = tile[j][m];   // coalesced
    }
}

// ---------------------------------------------------------------------------
// Kernel 1: all sparse chord weights, all 10 layers (h depends only on data).
// Block = (layer i, 8 rows, ALL 16 b). Thread = (b = t&15, jq = (t>>4)&3,
// nl = t>>6) computing 2 rows x 8 hidden units -> h[2][8] = 16 accum regs,
// ~50 VGPR total: spill-proof (rounds 2 & 4 died to scratch spill at 32+ row
// regs). W2T gather rows are shared across the 16 b-lanes (same address ->
// broadcast; 16x less L2 traffic than per-b blocks); j-quarter partials
// combined with shfl_xor(16/32) (lane = b + 16*jq).
// grid (NVEC/8, NW), block 256.
// ---------------------------------------------------------------------------
__global__ __launch_bounds__(256) void k_weights(
    const float* __restrict__ data,   // [B][NVEC][NDIM]
    const float* __restrict__ fW1,    // [NW][NDIM][NHID]
    const float* __restrict__ fb1,    // [NW][NHID]
    const float* __restrict__ W2T,    // [NW][NVEC][NHID]  (transposed fW2)
    const float* __restrict__ fb2,    // [NW][NVEC]
    float* __restrict__ Wsp)          // [NW][B][NVEC][WPAD]
{
    const int i = blockIdx.y;
    const int nbase = blockIdx.x * 8;
    const int t = threadIdx.x;
    const int b  = t & 15;
    const int jq = (t >> 4) & 3;
    const int nl = t >> 6;            // wave index; lane = b + 16*jq
    const int j0 = jq * 8;

    __shared__ float sW1[NDIM * NHID];   // [d][j], 8 KB
    __shared__ float sb1[NHID];
    {
        const float4* w1v = (const float4*)(fW1 + (size_t)i * NDIM * NHID);
        float4* s4 = (float4*)sW1;
        for (int k = t; k < NDIM * NHID / 4; k += 256) s4[k] = w1v[k];
        if (t < NHID) sb1[t] = fb1[i * NHID + t];
    }
    __syncthreads();

    float h[2][8];
    #pragma unroll
    for (int r = 0; r < 2; ++r)
        #pragma unroll
        for (int jj = 0; jj < 8; ++jj) h[r][jj] = sb1[j0 + jj];

    const int n0 = nbase + nl * 2;
    const float4* arow0 = (const float4*)(data + ((size_t)(b * NVEC) + n0) * NDIM);
    const float4* arow1 = (const float4*)(data + ((size_t)(b * NVEC) + n0 + 1) * NDIM);

    #pragma unroll 4
    for (int g = 0; g < 16; ++g) {       // 4 d-dims per iteration
        float4 a0 = arow0[g];
        float4 a1 = arow1[g];
        float as0[4] = {a0.x, a0.y, a0.z, a0.w};
        float as1[4] = {a1.x, a1.y, a1.z, a1.w};
        #pragma unroll
        for (int dk = 0; dk < 4; ++dk) {
            const float4* wp = (const float4*)(&sW1[(g * 4 + dk) * NHID + j0]);
            float4 w0 = wp[0], w1 = wp[1];
            const float wf[8] = {w0.x, w0.y, w0.z, w0.w, w1.x, w1.y, w1.z, w1.w};
            #pragma unroll
            for (int jj = 0; jj < 8; ++jj) {
                h[0][jj] += as0[dk] * wf[jj];
                h[1][jj] += as1[dk] * wf[jj];
            }
        }
    }

    // exact gelu
    #pragma unroll
    for (int r = 0; r < 2; ++r)
        #pragma unroll
        for (int jj = 0; jj < 8; ++jj) {
            float x = h[r][jj];
            h[r][jj] = 0.5f * x * (1.0f + erff(x * 0.70710678118654752f));
        }

    const float* w2t = W2T + (size_t)i * NVEC * NHID;
    const float* b2  = fb2 + (size_t)i * NVEC;
    #pragma unroll
    for (int r = 0; r < 2; ++r) {
        const int n = n0 + r;
        float* wout = Wsp + ((size_t)(i * BATCH + b) * NVEC + n) * WPAD;
        #pragma unroll
        for (int o = 0; o < NOFF; ++o) {
            int off = (o == 0) ? 0 : (1 << (o - 1));
            int m = (n + off) & (NVEC - 1);
            const float4* gp = (const float4*)(w2t + (size_t)m * NHID + j0);
            float4 g0 = gp[0], g1 = gp[1];
            float w = h[r][0] * g0.x + h[r][1] * g0.y + h[r][2] * g0.z + h[r][3] * g0.w
                    + h[r][4] * g1.x + h[r][5] * g1.y + h[r][6] * g1.z + h[r][7] * g1.w;
            w += __shfl_xor(w, 16, 64);   // combine jq bit 0
            w += __shfl_xor(w, 32, 64);   // combine jq bit 1
            if (jq == (o & 3)) wout[o] = w + b2[m];
        }
    }
}

// ---------------------------------------------------------------------------
// Kernel 2: FUSED 10-layer chain + final-projection partials.
// Block = (b, 4-dim chunk): V[1024][4] slice closed under the chord gather,
// kept in LDS float4 (all gathers aligned ds_read_b128). 1024 threads =
// 16 waves. Next layer's 11 weights (3 float4, row-padded) prefetched into
// registers so the loads are in flight across the barrier. 1 barrier/layer.
// grid (16 chunks, BATCH), block 1024.
// ---------------------------------------------------------------------------
__global__ __launch_bounds__(1024) void k_chain(
    const float* __restrict__ data,   // [B][NVEC][NDIM]
    const float* __restrict__ Wsp,    // [NW][B][NVEC][WPAD]
    const float* __restrict__ Wf,     // [NVEC*NDIM][NCLS]
    float* __restrict__ part)         // [B][16][NCLS]
{
    const int chunk = blockIdx.x;
    const int b     = blockIdx.y;
    const int d0    = chunk * 4;
    const int n     = threadIdx.x;

    __shared__ float4 bufA[NVEC];
    __shared__ float4 bufB[NVEC];

    bufA[n] = *(const float4*)(data + ((size_t)(b * NVEC) + n) * NDIM + d0);

    // prefetch layer NW-1 weights
    const float4* wp = (const float4*)(Wsp + ((size_t)((NW - 1) * BATCH + b) * NVEC + n) * WPAD);
    float4 wa = wp[0], wb4 = wp[1], wc = wp[2];
    __syncthreads();

    float4* cur = bufA;
    float4* nxt = bufB;

    for (int l = 0; l < NW; ++l) {
        float4 na, nb, nc;
        if (l < NW - 1) {   // prefetch next layer (in flight across barrier)
            const float4* wpn = (const float4*)(
                Wsp + ((size_t)((NW - 2 - l) * BATCH + b) * NVEC + n) * WPAD);
            na = wpn[0]; nb = wpn[1]; nc = wpn[2];
        }
        const float wgt[12] = {wa.x, wa.y, wa.z, wa.w,
                               wb4.x, wb4.y, wb4.z, wb4.w,
                               wc.x, wc.y, wc.z, wc.w};
        float4 v0 = cur[n];
        float4 acc;
        acc.x = v0.x + wgt[0] * v0.x;
        acc.y = v0.y + wgt[0] * v0.y;
        acc.z = v0.z + wgt[0] * v0.z;
        acc.w = v0.w + wgt[0] * v0.w;
        #pragma unroll
        for (int o = 1; o < NOFF; ++o) {
            int off = 1 << (o - 1);
            float4 vv = cur[(n + off) & (NVEC - 1)];
            acc.x += wgt[o] * vv.x; acc.y += wgt[o] * vv.y;
            acc.z += wgt[o] * vv.z; acc.w += wgt[o] * vv.w;
        }
        nxt[n] = acc;
        __syncthreads();
        float4* tmp = cur; cur = nxt; nxt = tmp;
        if (l < NW - 1) { wa = na; wb4 = nb; wc = nc; }
    }

    // fused final projection partial over this (b, d-chunk)
    float p[NCLS];
    #pragma unroll
    for (int c = 0; c < NCLS; ++c) p[c] = 0.0f;
    {
        float4 vv = cur[n];
        float vs[4] = {vv.x, vv.y, vv.z, vv.w};
        const float4* wfv = (const float4*)(Wf + ((size_t)(n * NDIM + d0)) * NCLS);
        float wf[40];
        #pragma unroll
        for (int k = 0; k < 10; ++k) {
            float4 u = wfv[k];
            wf[k * 4 + 0] = u.x; wf[k * 4 + 1] = u.y;
            wf[k * 4 + 2] = u.z; wf[k * 4 + 3] = u.w;
        }
        #pragma unroll
        for (int d = 0; d < 4; ++d)
            #pragma unroll
            for (int cls = 0; cls < NCLS; ++cls)
                p[cls] += vs[d] * wf[d * NCLS + cls];
    }

    // reduce 1024 threads -> 10 values: wave shfl then cross-wave via LDS
    const int lane = n & 63, wv = n >> 6;   // 16 waves
    float* sred = (float*)nxt;              // dead buffer
    #pragma unroll
    for (int cls = 0; cls < NCLS; ++cls) {
        float v = p[cls];
        #pragma unroll
        for (int s = 32; s > 0; s >>= 1) v += __shfl_down(v, s, 64);
        if (lane == 0) sred[wv * NCLS + cls] = v;
    }
    __syncthreads();
    if (n < NCLS) {
        float s = 0.0f;
        #pragma unroll
        for (int w = 0; w < 16; ++w) s += sred[w * NCLS + n];
        part[(size_t)(b * 16 + chunk) * NCLS + n] = s;
    }
}

// ---------------------------------------------------------------------------
__global__ __launch_bounds__(256) void k_finish(
    const float* __restrict__ part, const float* __restrict__ bias,
    float* __restrict__ out)
{
    int t = threadIdx.x;
    if (t < BATCH * NCLS) {
        int b = t / NCLS, cls = t % NCLS;
        float s = bias[cls];
        #pragma unroll
        for (int ch = 0; ch < 16; ++ch) s += part[(size_t)(b * 16 + ch) * NCLS + cls];
        out[t] = s;
    }
}

// ---------------------------------------------------------------------------
extern "C" void kernel_launch(void* const* d_in, const int* in_sizes, int n_in,
                              void* d_out, int out_size, void* d_ws, size_t ws_size,
                              hipStream_t stream) {
    const float* data = (const float*)d_in[0];
    const float* fW1  = (const float*)d_in[1];
    const float* fb1  = (const float*)d_in[2];
    const float* fW2  = (const float*)d_in[3];
    const float* fb2  = (const float*)d_in[4];
    const float* fWf  = (const float*)d_in[5];
    const float* fbf  = (const float*)d_in[6];
    float* out = (float*)d_out;

    float* ws   = (float*)d_ws;
    float* Wsp  = ws;                                         // NW*B*NVEC*WPAD = 1,966,080 f
    float* W2T  = Wsp + (size_t)NW * BATCH * NVEC * WPAD;     // NW*NVEC*NHID  =   327,680 f
    float* part = W2T + (size_t)NW * NVEC * NHID;             // 2,560 f

    k_transpose<<<dim3(NVEC / 64, NW), 256, 0, stream>>>(fW2, W2T);
    k_weights<<<dim3(NVEC / 8, NW), 256, 0, stream>>>(
        data, fW1, fb1, W2T, fb2, Wsp);
    k_chain<<<dim3(NDIM / 4, BATCH), 1024, 0, stream>>>(data, Wsp, fWf, part);
    k_finish<<<dim3(1), 256, 0, stream>>>(part, fbf, out);
}